// Round 7
// baseline (432.222 us; speedup 1.0000x reference)
//
#include <hip/hip_runtime.h>

#define H 512
#define W 512
#define K 5
#define PAD 2
#define TROWS 4                       // output rows per block
#define IROWS (TROWS + K - 1)         // 8 staged input rows
#define XPT 4                         // output cols per thread (one float4)
#define NCHUNK (IROWS * W * 4 / 16)   // 1024 16-byte chunks per tile
#define CPT (NCHUNK / 256)            // 4 chunks staged per thread

typedef float vf4 __attribute__((ext_vector_type(4)));

// Round-4 post-mortem: DMA staging streams at 4.2 TB/s (vs 3.2 for register
// pipelining) but hbm_bytes inflated to 383 MB -- WRITE_SIZE was 1.82x the
// output (nontemporal-store suspect), killing the gain. This round keeps the
// global_load_lds structure (async DMA, cannot be re-sunk by the compiler;
// one vmcnt(0) drain per block; latency hiding via TLP) and changes:
//  (1) plain temporal stores -- output buffers in L2, written back once.
//      Prediction: WRITE_SIZE returns to 131072 KB. If not, the inflation
//      is in the DMA path and next step is reg->ds_write staging.
//  (2) TROWS=4 (16 KB LDS): 8 blocks/CU and 16384 blocks for deeper
//      overlap of stage-drains with compute. Halo re-reads (2x demand)
//      are L3-absorbed per rounds 0/2 (FETCH stayed <= input at 2x).
// Same clamp+mask numerics and FMA order as all passing rounds.
// (Rounds 5/6 were container-acquisition infra failures; this is an
// unmodified third submission of the same experiment. If it fails again,
// round 7 bisects from the round-4 known-good source.)
__global__ __launch_bounds__(256, 8) void conv5x5_kernel(
    const float* __restrict__ X, const float* __restrict__ ker,
    float* __restrict__ out)
{
    __shared__ float tile[IROWS][W];          // 16 KB

    const int tx  = threadIdx.x;              // 0..255
    const int y0  = blockIdx.x * TROWS;       // 0,4,...,508
    const int img = blockIdx.y;               // 0..127

    const float* Xp = X   + (size_t)img * H * W;
    float*       Op = out + (size_t)img * H * W;

    // ---- async stage: 8 full-width rows -> LDS (no VGPR destination) ----
    // wave lanes cover 64 consecutive 16B chunks: LDS dest = uniform base
    // + lane*16 (the global_load_lds contiguity requirement).
    #pragma unroll
    for (int k = 0; k < CPT; ++k) {
        const int c   = tx + 256 * k;         // chunk id 0..1023
        const int rr  = c >> 7;               // staged row 0..7 (128 chunks/row)
        const int c16 = c & 127;              // 16B chunk within row
        int yr = y0 - PAD + rr;
        yr = yr < 0 ? 0 : (yr > H - 1 ? H - 1 : yr);   // clamped; masked at use
        const float* src = Xp + (size_t)yr * W + c16 * 4;
        __builtin_amdgcn_global_load_lds(
            (const __attribute__((address_space(1))) void*)src,
            (__attribute__((address_space(3))) void*)&tile[rr][c16 * 4],
            16, 0, 0);
    }

    // kernel coeffs: uniform address -> scalar loads into SGPRs (overlaps DMA)
    float kk[K][K];
    #pragma unroll
    for (int i = 0; i < K; ++i)
        #pragma unroll
        for (int j = 0; j < K; ++j)
            kk[i][j] = ker[i * K + j];

    __syncthreads();                          // vmcnt(0) drain + barrier

    // ---- compute from LDS: 2 output rows x 4 cols per thread ----
    const int q  = tx & 127;                  // vf4 column 0..127
    const int ty = tx >> 7;                   // 0..1 (2 output rows each)
    const int qL = (q == 0)   ? 0 : q - 1;    // clamped: always in-bounds
    const int qR = (q == 127) ? q : q + 1;
    const float mLo = (q == 0)   ? 0.f : 1.f; // zero v[0],v[1] at left edge
    const float mHi = (q == 127) ? 0.f : 1.f; // zero v[6],v[7] at right edge
    const int rbase = ty * 2;                 // first output row (0 or 2)

    float acc[2][XPT];
    #pragma unroll
    for (int o = 0; o < 2; ++o)
        #pragma unroll
        for (int j = 0; j < XPT; ++j)
            acc[o][j] = 0.f;

    #pragma unroll
    for (int r = 0; r < K + 1; ++r) {         // 6 input rows per thread
        const int lr = rbase + r;             // LDS row 0..7
        const int yr = y0 - PAD + lr;         // global input row
        const float mR = (yr >= 0 && yr < H) ? 1.f : 0.f;
        const vf4* rp = (const vf4*)&tile[lr][0];
        const vf4 Lv = rp[qL];
        const vf4 Mv = rp[q];
        const vf4 Rv = rp[qR];
        const float mA = mLo * mR;
        const float mC = mHi * mR;
        // window v[0..7] = input cols q*4-2 .. q*4+5 (same values as before)
        float v[8];
        v[0] = Lv.z * mA;  v[1] = Lv.w * mA;
        v[2] = Mv.x * mR;  v[3] = Mv.y * mR;
        v[4] = Mv.z * mR;  v[5] = Mv.w * mR;
        v[6] = Rv.x * mC;  v[7] = Rv.y * mC;

        // input tile row r feeds kernel-row kr = r - o of output row o.
        // Per output row: kr = 0..4, c = 0..4 -- identical order/numerics.
        #pragma unroll
        for (int o = 0; o < 2; ++o) {
            const int kr = r - o;
            if (kr >= 0 && kr < K) {
                #pragma unroll
                for (int c = 0; c < K; ++c)
                    #pragma unroll
                    for (int j = 0; j < XPT; ++j)
                        acc[o][j] = fmaf(v[j + c], kk[kr][c], acc[o][j]);
            }
        }
    }

    #pragma unroll
    for (int o = 0; o < 2; ++o) {
        vf4 st = {acc[o][0], acc[o][1], acc[o][2], acc[o][3]};
        *(vf4*)(Op + (size_t)(y0 + rbase + o) * W + q * XPT) = st;  // temporal
    }
}

extern "C" void kernel_launch(void* const* d_in, const int* in_sizes, int n_in,
                              void* d_out, int out_size, void* d_ws, size_t ws_size,
                              hipStream_t stream) {
    const float* X   = (const float*)d_in[0];
    const float* ker = (const float*)d_in[1];
    float* out = (float*)d_out;

    dim3 block(256, 1, 1);
    dim3 grid(H / TROWS, 4 * 32, 1);          // (128, 128): y-tile x image
    hipLaunchKernelGGL(conv5x5_kernel, grid, block, 0, stream, X, ker, out);
}

// Round 9
// 231.649 us; speedup vs baseline: 1.8658x; 1.8658x over previous
//
#include <hip/hip_runtime.h>

#define H 512
#define W 512
#define K 5
#define PAD 2
#define RPT 4             // output rows per thread
#define XPT 4             // output cols per thread (one float4)
#define NR (RPT + K - 1)  // 8 input rows per thread

typedef float vf4 __attribute__((ext_vector_type(4)));
typedef float vf2 __attribute__((ext_vector_type(2)));

// Rounds 4/7 killed the DMA-staging path: it inflates HBM traffic
// (WRITE 238->751 MB, FETCH 467 MB) and lost to the register kernel's
// exact-once 231 MB. Rounds 1-3 showed the register kernel's real problem:
// latency-bound (~3 TB/s eff, all pipes <40%) because hipcc re-sinks
// source-level prefetches to point-of-use. Fix here is the AITER pattern
// the compiler cannot defeat: loads issued as ORDERED inline-asm
// global_load (opaque, volatile, memory-clobber -> cannot be re-sunk),
// then 8 consume stages each gated by a literal counted
// s_waitcnt vmcnt(21-3r) + sched_barrier(0) (rule #18). Row r computes
// while rows r+1..7 are still in flight; vmcnt never drains mid-pipe.
// Geometry/numerics identical to the best-measured round-0 shape.
// (Round 8 was a container-acquisition infra failure -- same signature as
// rounds 5/6, which an identical resubmission then proved benign. This is
// an unmodified resubmission; audit found no hang/OOB/bookkeeping hazard.)
__global__ __launch_bounds__(256, 4) void conv5x5_kernel(
    const float* __restrict__ X, const float* __restrict__ ker,
    float* __restrict__ out)
{
    const int tx  = threadIdx.x;                      // 0..63
    const int xb  = (blockIdx.x * 64 + tx) * XPT;     // 0,4,...,508
    const int y0  = blockIdx.y * (4 * RPT) + threadIdx.y * RPT;
    const int img = blockIdx.z;                       // 0..127

    const float* Xp = X   + (size_t)img * H * W;      // uniform -> SGPR pair
    float*       Op = out + (size_t)img * H * W;

    // kernel coeffs (uniform -> s_load/SGPR); retired by the fence below
    float kk[K][K];
    #pragma unroll
    for (int i = 0; i < K; ++i)
        #pragma unroll
        for (int j = 0; j < K; ++j)
            kk[i][j] = ker[i * K + j];

    // clamped halo columns + edge masks (same values as all passing rounds)
    const int xL = (xb == 0) ? 0 : xb - 2;            // cols xb-2, xb-1
    const int xR = (xb == W - XPT) ? xb : xb + 4;     // cols xb+4, xb+5
    const float mLo = (xb == 0) ? 0.f : 1.f;
    const float mHi = (xb == W - XPT) ? 0.f : 1.f;

    // per-row 32-bit byte offsets (saddr form: base SGPR + voffset VGPR)
    unsigned oL[NR], oM[NR], oR[NR];
    float rmask[NR];
    #pragma unroll
    for (int r = 0; r < NR; ++r) {
        const int yr = y0 - PAD + r;
        const int yc = yr < 0 ? 0 : (yr > H - 1 ? H - 1 : yr);
        rmask[r] = (yr >= 0 && yr < H) ? 1.f : 0.f;
        const unsigned rb = (unsigned)(yc * W) * 4u;
        oL[r] = rb + (unsigned)xL * 4u;
        oM[r] = rb + (unsigned)xb * 4u;
        oR[r] = rb + (unsigned)xR * 4u;
    }

    // start vmcnt bookkeeping from 0 (kk s_loads + anything else retired)
    asm volatile("s_waitcnt vmcnt(0) lgkmcnt(0)" ::: "memory");

    vf2 hl0, hl1, hl2, hl3, hl4, hl5, hl6, hl7;
    vf4 mm0, mm1, mm2, mm3, mm4, mm5, mm6, mm7;
    vf2 hr0, hr1, hr2, hr3, hr4, hr5, hr6, hr7;

    // ---- issue phase: 24 loads, strict program order (3 per row) ----
#define ISSUE(rr)                                                              \
    asm volatile("global_load_dwordx2 %0, %1, %2"                              \
                 : "=v"(hl##rr) : "v"(oL[rr]), "s"(Xp) : "memory");            \
    asm volatile("global_load_dwordx4 %0, %1, %2"                              \
                 : "=v"(mm##rr) : "v"(oM[rr]), "s"(Xp) : "memory");            \
    asm volatile("global_load_dwordx2 %0, %1, %2"                              \
                 : "=v"(hr##rr) : "v"(oR[rr]), "s"(Xp) : "memory")

    ISSUE(0); ISSUE(1); ISSUE(2); ISSUE(3);
    ISSUE(4); ISSUE(5); ISSUE(6); ISSUE(7);
#undef ISSUE

    float acc[RPT][XPT];
    #pragma unroll
    for (int o = 0; o < RPT; ++o)
        #pragma unroll
        for (int j = 0; j < XPT; ++j)
            acc[o][j] = 0.f;

    // ---- consume phase: row r gated on vmcnt(21-3r); rest stay in flight ----
#define CONSUME(rr, WN)                                                        \
    do {                                                                       \
        asm volatile("s_waitcnt vmcnt(" #WN ")" ::: "memory");                 \
        __builtin_amdgcn_sched_barrier(0);                                     \
        const float mR = rmask[rr];                                            \
        const float mA = mLo * mR;                                             \
        const float mC = mHi * mR;                                             \
        float v[8];                                                            \
        v[0] = hl##rr.x * mA;  v[1] = hl##rr.y * mA;                           \
        v[2] = mm##rr.x * mR;  v[3] = mm##rr.y * mR;                           \
        v[4] = mm##rr.z * mR;  v[5] = mm##rr.w * mR;                           \
        v[6] = hr##rr.x * mC;  v[7] = hr##rr.y * mC;                           \
        _Pragma("unroll")                                                      \
        for (int o = 0; o < RPT; ++o) {                                        \
            const int kr = (rr) - o;       /* compile-time after unroll */     \
            if (kr >= 0 && kr < K) {                                           \
                _Pragma("unroll")                                              \
                for (int c = 0; c < K; ++c)                                    \
                    _Pragma("unroll")                                          \
                    for (int j = 0; j < XPT; ++j)                              \
                        acc[o][j] = fmaf(v[j + c], kk[kr][c], acc[o][j]);      \
            }                                                                  \
        }                                                                      \
    } while (0)

    CONSUME(0, 21); CONSUME(1, 18); CONSUME(2, 15); CONSUME(3, 12);
    CONSUME(4,  9); CONSUME(5,  6); CONSUME(6,  3); CONSUME(7,  0);
#undef CONSUME

    // NT stores: WRITE_SIZE == 131072 KB exactly in every register round
    #pragma unroll
    for (int o = 0; o < RPT; ++o) {
        vf4 st = {acc[o][0], acc[o][1], acc[o][2], acc[o][3]};
        __builtin_nontemporal_store(st, (vf4*)(Op + (size_t)(y0 + o) * W + xb));
    }
}

extern "C" void kernel_launch(void* const* d_in, const int* in_sizes, int n_in,
                              void* d_out, int out_size, void* d_ws, size_t ws_size,
                              hipStream_t stream) {
    const float* X   = (const float*)d_in[0];
    const float* ker = (const float*)d_in[1];
    float* out = (float*)d_out;

    dim3 block(64, 4, 1);
    dim3 grid(W / (64 * XPT), H / (4 * RPT), 4 * 32);  // (2, 32, 128)
    hipLaunchKernelGGL(conv5x5_kernel, grid, block, 0, stream, X, ker, out);
}